// Round 1
// baseline (96002.655 us; speedup 1.0000x reference)
//
#include <hip/hip_runtime.h>
#include <math.h>

// ---------------------------------------------------------------------------
// R2P2_Dynamic: B=131072 independent GRU-ish recurrences, T=30 steps.
// Round 1: correct fp32 baseline. One persistent kernel; each block owns
// BT=16 batch rows; W_hh rows live in per-thread registers (neuron-owner);
// h / gate buffers / W1 / biases in dynamic LDS (118 KiB, opt-in).
// ---------------------------------------------------------------------------

constexpr int BTOT = 131072;
constexpr int TSTEPS = 30;
constexpr int H  = 150;
constexpr int G3 = 450;     // 3*H
constexpr int SD = 50;      // static dim, also MLP1 width
constexpr int BT = 16;      // batch rows per block
constexpr int NT = 512;     // threads per block

constexpr int HS  = 152;    // h row stride (floats)
constexpr int GS  = 452;    // ghs / gi_acc row stride
constexpr int SS  = 52;     // stat / o1 row stride
constexpr int W1S = 204;    // W1 row stride (row-major [50][204])

// LDS layout (float offsets)
constexpr int OFF_H     = 0;
constexpr int OFF_GHS   = OFF_H    + BT*HS;    // 2432
constexpr int OFF_GI    = OFF_GHS  + BT*GS;    // 9664
constexpr int OFF_STAT  = OFF_GI   + BT*GS;    // 16896
constexpr int OFF_O1    = OFF_STAT + BT*SS;    // 17728
constexpr int OFF_O2    = OFF_O1   + BT*SS;    // 18560
constexpr int OFF_W1    = OFF_O2   + BT*8;     // 18688 (16B aligned)
constexpr int OFF_BIH   = OFF_W1   + SD*W1S;   // 28888
constexpr int OFF_BHH   = OFF_BIH  + G3;       // 29338
constexpr int OFF_B1    = OFF_BHH  + G3;       // 29788
constexpr int OFF_W2    = OFF_B1   + SD;       // 29838
constexpr int OFF_B2    = OFF_W2   + 6*SD;     // 30138
constexpr int OFF_XPREV = OFF_B2   + 8;        // 30146
constexpr int OFF_DX    = OFF_XPREV + 2*BT;    // 30178
constexpr int OFF_XCUR  = OFF_DX    + 2*BT;    // 30210
constexpr int SMEM_FLOATS = OFF_XCUR + 2*BT;   // 30242
constexpr int SMEM_BYTES  = SMEM_FLOATS * 4;   // 120968 B

constexpr int SIG_OFF = TSTEPS * BTOT * 2;            // 7864320
constexpr int X_OFF   = SIG_OFF + TSTEPS * BTOT * 4;  // 23592960

__device__ __forceinline__ float softplusf(float v) {
    // log1p(exp(v)), stable form — matches jax.nn.softplus in fp32
    return fmaxf(v, 0.f) + log1pf(expf(-fabsf(v)));
}

__global__ __launch_bounds__(NT) void r2p2_kernel(
    const float* __restrict__ statp, const float* __restrict__ initv,
    const float* __restrict__ initp, const float* __restrict__ zp,
    const float* __restrict__ Wih,   const float* __restrict__ Whh,
    const float* __restrict__ bih,   const float* __restrict__ bhh,
    const float* __restrict__ W1,    const float* __restrict__ b1,
    const float* __restrict__ W2,    const float* __restrict__ b2,
    float* __restrict__ out)
{
    extern __shared__ float sm[];
    const int t   = threadIdx.x;
    const int bg0 = blockIdx.x * BT;

    // ---- persistent register weights: W_hh row t (t < 450) ----
    float wh[H];
    if (t < G3) {
        const float2* wrow = (const float2*)(Whh + t * H);  // t*150*4 B, 8B aligned
        #pragma unroll
        for (int k2 = 0; k2 < H/2; ++k2) {
            float2 v = wrow[k2];
            wh[2*k2]   = v.x;
            wh[2*k2+1] = v.y;
        }
    }

    // ---- LDS init ----
    for (int i = t; i < BT*HS; i += NT) sm[OFF_H  + i] = 0.f;
    for (int i = t; i < BT*GS; i += NT) sm[OFF_GI + i] = 0.f;
    for (int i = t; i < SD*200; i += NT) {
        int j = i / 200, k = i - j*200;
        sm[OFF_W1 + j*W1S + k] = W1[i];
    }
    for (int i = t; i < BT*SD; i += NT) {
        int b = i / SD, k = i - b*SD;
        sm[OFF_STAT + b*SS + k] = statp[(bg0 + b)*SD + k];
    }
    if (t < G3) { sm[OFF_BIH + t] = bih[t]; sm[OFF_BHH + t] = bhh[t]; }
    if (t < SD)  sm[OFF_B1 + t] = b1[t];
    if (t < 6*SD) sm[OFF_W2 + t] = W2[t];
    if (t < 6)   sm[OFF_B2 + t] = b2[t];
    if (t < 2*BT) {
        sm[OFF_XPREV + t] = initp[bg0*2 + t];
        sm[OFF_DX    + t] = initv[bg0*2 + t];
    }
    __syncthreads();

    for (int step = 0; step < TSTEPS; ++step) {
        // ---- phase 1: gh[b][t] = dot(W_hh[t,:], h[b,:]) ----
        if (t < G3) {
            for (int b = 0; b < BT; ++b) {
                const float* hb = &sm[OFF_H + b*HS];
                float s = 0.f;
                #pragma unroll
                for (int k = 0; k < H; ++k) s = fmaf(wh[k], hb[k], s);
                sm[OFF_GHS + b*GS + t] = s;
            }
        }
        __syncthreads();

        // ---- phase 2: GRU gates + h update ----
        for (int it = t; it < BT*H; it += NT) {
            int b = it / H, u = it - b*H;
            float gir = sm[OFF_GI  + b*GS + u]        + sm[OFF_BIH + u];
            float giz = sm[OFF_GI  + b*GS + u + H]    + sm[OFF_BIH + u + H];
            float gin = sm[OFF_GI  + b*GS + u + 2*H]  + sm[OFF_BIH + u + 2*H];
            float ghr = sm[OFF_GHS + b*GS + u]        + sm[OFF_BHH + u];
            float ghz = sm[OFF_GHS + b*GS + u + H]    + sm[OFF_BHH + u + H];
            float ghn = sm[OFF_GHS + b*GS + u + 2*H]  + sm[OFF_BHH + u + 2*H];
            float r  = 1.f / (1.f + expf(-(gir + ghr)));
            float zg = 1.f / (1.f + expf(-(giz + ghz)));
            float n  = tanhf(gin + r*ghn);
            float hold = sm[OFF_H + b*HS + u];
            sm[OFF_H + b*HS + u] = (1.f - zg)*n + zg*hold;
        }
        __syncthreads();

        // ---- phase 3: o1 = softplus(W1 @ [h, static] + b1) ----
        for (int it = t; it < BT*SD; it += NT) {
            int b = it / SD, j = it - b*SD;
            const float* w1r = &sm[OFF_W1 + j*W1S];
            const float* hb  = &sm[OFF_H + b*HS];
            const float* sb  = &sm[OFF_STAT + b*SS];
            float acc = sm[OFF_B1 + j];
            #pragma unroll
            for (int k = 0; k < H; ++k)  acc = fmaf(w1r[k], hb[k], acc);
            #pragma unroll
            for (int k = 0; k < SD; ++k) acc = fmaf(w1r[H + k], sb[k], acc);
            sm[OFF_O1 + b*SS + j] = softplusf(acc);
        }
        __syncthreads();

        // ---- phase 4: o2 = softplus(W2 @ o1 + b2) ----
        if (t < BT*6) {
            int b = t / 6, m = t - b*6;
            const float* w2r = &sm[OFF_W2 + m*SD];
            const float* o1b = &sm[OFF_O1 + b*SS];
            float acc = sm[OFF_B2 + m];
            #pragma unroll
            for (int k = 0; k < SD; ++k) acc = fmaf(w2r[k], o1b[k], acc);
            sm[OFF_O2 + b*8 + m] = softplusf(acc);
        }
        __syncthreads();

        // ---- phase 5: expm_sym2x2, mu, x, outputs ----
        if (t < BT) {
            const int b  = t;
            const int bg = bg0 + b;
            float mh0 = sm[OFF_O2 + b*8 + 0];
            float mh1 = sm[OFF_O2 + b*8 + 1];
            float s2  = sm[OFF_O2 + b*8 + 2];
            float s3  = sm[OFF_O2 + b*8 + 3];
            float s4  = sm[OFF_O2 + b*8 + 4];
            float s5  = sm[OFF_O2 + b*8 + 5];
            // S = sig_hat + sig_hat^T ; sig_hat = [[s2,s3],[s4,s5]]
            float a  = 2.f*s2, bb = s3 + s4, c = 2.f*s5;
            float htr = 0.5f*(a + c), hdf = 0.5f*(a - c);
            float disc = sqrtf(hdf*hdf + bb*bb);
            float d    = fmaxf(disc, 1e-12f);
            float ep = expf(d), em = expf(-d);
            float sinhc = (0.5f*(ep - em)) / d;
            float coshd = 0.5f*(ep + em);       // cosh(disc)==cosh(d) in fp32
            float scale = expf(htr);
            float m00 = scale*(coshd + sinhc*hdf);
            float m11 = scale*(coshd - sinhc*hdf);
            float m01 = scale*(sinhc*bb);

            float z0 = zp[(step*BTOT + bg)*2 + 0];
            float z1 = zp[(step*BTOT + bg)*2 + 1];
            float xp0 = sm[OFF_XPREV + 2*b], xp1 = sm[OFF_XPREV + 2*b + 1];
            float mu0 = xp0 + sm[OFF_DX + 2*b]     + mh0;
            float mu1 = xp1 + sm[OFF_DX + 2*b + 1] + mh1;
            float x0 = fmaf(m00, z0, fmaf(m01, z1, mu0));
            float x1 = fmaf(m01, z0, fmaf(m11, z1, mu1));

            const int oi = step*BTOT + bg;
            out[oi*2 + 0] = mu0;
            out[oi*2 + 1] = mu1;
            out[SIG_OFF + oi*4 + 0] = m00;
            out[SIG_OFF + oi*4 + 1] = m01;
            out[SIG_OFF + oi*4 + 2] = m01;
            out[SIG_OFF + oi*4 + 3] = m11;
            out[X_OFF + oi*2 + 0] = x0;
            out[X_OFF + oi*2 + 1] = x1;

            sm[OFF_XCUR + 2*b]     = x0;
            sm[OFF_XCUR + 2*b + 1] = x1;
            sm[OFF_DX + 2*b]       = x0 - xp0;
            sm[OFF_DX + 2*b + 1]   = x1 - xp1;
            sm[OFF_XPREV + 2*b]     = x0;
            sm[OFF_XPREV + 2*b + 1] = x1;
        }
        __syncthreads();

        // ---- phase 6: gi_acc += W_ih[:, 2*step:2*step+2] @ x_step ----
        // (next phase-1 does not touch GI; next phase-2 is past a barrier)
        if (t < G3) {
            float2 w = *(const float2*)(Wih + t*(2*TSTEPS) + 2*step);
            for (int b = 0; b < BT; ++b) {
                float xv0 = sm[OFF_XCUR + 2*b];
                float xv1 = sm[OFF_XCUR + 2*b + 1];
                sm[OFF_GI + b*GS + t] += w.x*xv0 + w.y*xv1;
            }
        }
    }
}

extern "C" void kernel_launch(void* const* d_in, const int* in_sizes, int n_in,
                              void* d_out, int out_size, void* d_ws, size_t ws_size,
                              hipStream_t stream) {
    const float* statp = (const float*)d_in[0];
    const float* initv = (const float*)d_in[1];
    const float* initp = (const float*)d_in[2];
    const float* zp    = (const float*)d_in[3];
    const float* Wih   = (const float*)d_in[4];
    const float* Whh   = (const float*)d_in[5];
    const float* bih   = (const float*)d_in[6];
    const float* bhh   = (const float*)d_in[7];
    const float* W1    = (const float*)d_in[8];
    const float* b1    = (const float*)d_in[9];
    const float* W2    = (const float*)d_in[10];
    const float* b2    = (const float*)d_in[11];
    float* out = (float*)d_out;

    (void)hipFuncSetAttribute((const void*)r2p2_kernel,
                              hipFuncAttributeMaxDynamicSharedMemorySize,
                              SMEM_BYTES);

    dim3 grid(BTOT / BT);   // 8192
    dim3 block(NT);         // 512
    r2p2_kernel<<<grid, block, SMEM_BYTES, stream>>>(
        statp, initv, initp, zp, Wih, Whh, bih, bhh, W1, b1, W2, b2, out);
}

// Round 2
// 8425.002 us; speedup vs baseline: 11.3950x; 11.3950x over previous
//
#include <hip/hip_runtime.h>
#include <math.h>

// ---------------------------------------------------------------------------
// R2P2_Dynamic round 2: MFMA (fp16 hi/lo split) for the recurrent GEMM and
// the MLP1 GEMM. Persistent 256-block grid (1 block/CU), 32 batch-groups of
// BT=16. W_hh fragments in registers; W_ih pre-transposed via prep kernel.
// ---------------------------------------------------------------------------

typedef _Float16 f16;
typedef _Float16 f16x8 __attribute__((ext_vector_type(8)));
typedef float    f32x4 __attribute__((ext_vector_type(4)));

constexpr int BTOT = 131072;
constexpr int TSTEPS = 30;
constexpr int H   = 150;
constexpr int SD  = 50;
constexpr int BT  = 16;
constexpr int NT  = 512;
constexpr int NBLK = 256;
constexpr int NGRP = BTOT / (NBLK * BT);   // 32

constexpr int HP  = 160;   // per-gate padded width
constexpr int NP  = 480;   // padded 3H (30 N-tiles of 16)
constexpr int KP3 = 224;   // phase-3 K: [h(150) pad 160 | static(50) pad 64]

// strides
constexpr int H32S = 152;  // h fp32 row stride (floats)
constexpr int AHS  = 232;  // fp16 A-buffer row stride (elements); 464 B = 29*16
constexpr int GIS  = 482;  // GI / GHS row stride (floats) -> conflict-free acc writes
constexpr int O1S  = 52;

// LDS byte offsets (all 16-aligned)
constexpr int OFF_H32  = 0;                              // 16*152*4 = 9728
constexpr int OFF_HHI  = OFF_H32  + BT*H32S*4;           // 9728
constexpr int OFF_HLO  = OFF_HHI  + BT*AHS*2;            // 17152
constexpr int OFF_GI   = OFF_HLO  + BT*AHS*2;            // 24576
constexpr int OFF_GHS  = OFF_GI   + BT*GIS*4;            // 55424
constexpr int OFF_W1   = OFF_GHS  + BT*GIS*4;            // 86272
constexpr int OFF_O1   = OFF_W1   + 64*AHS*2;            // 115968
constexpr int OFF_O2   = OFF_O1   + BT*O1S*4;            // 119296
constexpr int OFF_BIHP = OFF_O2   + BT*8*4;              // 119808
constexpr int OFF_BHHP = OFF_BIHP + NP*4;                // 121728
constexpr int OFF_B1   = OFF_BHHP + NP*4;                // 123648
constexpr int OFF_W2   = OFF_B1   + 52*4;                // 123856
constexpr int OFF_B2   = OFF_W2   + 300*4;               // 125056
constexpr int OFF_XP   = OFF_B2   + 32;                  // 125088
constexpr int OFF_DX   = OFF_XP   + 128;                 // 125216
constexpr int OFF_XC   = OFF_DX   + 128;                 // 125344
constexpr int SMEM_BYTES = OFF_XC + 128;                 // 125472 B < 160 KiB

constexpr int SIG_OFF = TSTEPS * BTOT * 2;
constexpr int X_OFF   = SIG_OFF + TSTEPS * BTOT * 4;

__device__ __forceinline__ float softplusf(float v) {
    return fmaxf(v, 0.f) + log1pf(expf(-fabsf(v)));
}

// --- prep: W_ih [450][60] -> ws [30 steps][480 padded rows][2] fp32 ---------
__global__ void r2p2_prep(const float* __restrict__ Wih, float* __restrict__ ws) {
    int id = blockIdx.x * 256 + threadIdx.x;          // over 30*480
    if (id >= TSTEPS * NP) return;
    int s = id / NP, tp = id - s * NP;
    int g = tp / HP, off = tp - g * HP;
    float2 v = make_float2(0.f, 0.f);
    if (off < H) {
        const float* row = Wih + (g * H + off) * (2 * TSTEPS);
        v.x = row[2 * s];
        v.y = row[2 * s + 1];
    }
    ((float2*)ws)[id] = v;
}

__global__ __launch_bounds__(NT, 2) void r2p2_main(
    const float* __restrict__ statp, const float* __restrict__ initv,
    const float* __restrict__ initp, const float* __restrict__ zp,
    const float* __restrict__ Whh,
    const float* __restrict__ bih,   const float* __restrict__ bhh,
    const float* __restrict__ W1,    const float* __restrict__ b1,
    const float* __restrict__ W2,    const float* __restrict__ b2,
    const float* __restrict__ wihT,  float* __restrict__ out)
{
    extern __shared__ char smc[];
    float* sh32 = (float*)(smc + OFF_H32);
    f16*   shhi = (f16*)  (smc + OFF_HHI);
    f16*   shlo = (f16*)  (smc + OFF_HLO);
    float* sgi  = (float*)(smc + OFF_GI);
    float* sghs = (float*)(smc + OFF_GHS);
    f16*   sw1  = (f16*)  (smc + OFF_W1);
    float* so1  = (float*)(smc + OFF_O1);
    float* so2  = (float*)(smc + OFF_O2);
    float* sbih = (float*)(smc + OFF_BIHP);
    float* sbhh = (float*)(smc + OFF_BHHP);
    float* sb1  = (float*)(smc + OFF_B1);
    float* sw2  = (float*)(smc + OFF_W2);
    float* sb2  = (float*)(smc + OFF_B2);
    float* sxp  = (float*)(smc + OFF_XP);
    float* sdx  = (float*)(smc + OFF_DX);
    float* sxc  = (float*)(smc + OFF_XC);

    const int t  = threadIdx.x;
    const int w  = t >> 6;         // wave 0..7
    const int l  = t & 63;
    const int lr = l & 15;         // fragment row/col index
    const int lq = l >> 4;         // k-quarter

    // ---- W_hh -> per-wave register fragments (fp16 hi/lo), once ----
    // waves 0..6 own N-tiles 4w..4w+3; wave 7 owns tiles 28,29.
    f16x8 bhi[4][5], blo[4][5];
    #pragma unroll
    for (int c = 0; c < 4; ++c) {
        const int ti = w * 4 + c;
        if (ti < 30) {
            const int g   = ti / 10, it9 = ti % 10;
            const int nr  = it9 * 16 + lr;            // row within gate (0..159)
            const bool rok = nr < H;
            const float* wr = Whh + (g * H + nr) * H; // safe: only read if rok
            #pragma unroll
            for (int kk = 0; kk < 5; ++kk) {
                #pragma unroll
                for (int j = 0; j < 8; ++j) {
                    const int cc = kk * 32 + lq * 8 + j;
                    float v = (rok && cc < H) ? wr[cc] : 0.f;
                    f16 hi = (f16)v;
                    bhi[c][kk][j] = hi;
                    blo[c][kk][j] = (f16)(v - (float)hi);
                }
            }
        } else {
            #pragma unroll
            for (int kk = 0; kk < 5; ++kk) { bhi[c][kk] = (f16x8)(f16)0.f; blo[c][kk] = (f16x8)(f16)0.f; }
        }
    }

    // ---- global constants -> LDS, once ----
    for (int i = t; i < 64 * KP3; i += NT) {            // W1 fp16 padded [64][224]
        int r = i / KP3, k = i - r * KP3;
        float v = 0.f;
        if (r < SD) {
            if (k < H) v = W1[r * 200 + k];
            else if (k >= HP && k < HP + SD) v = W1[r * 200 + H + (k - HP)];
        }
        sw1[r * AHS + k] = (f16)v;
    }
    for (int i = t; i < NP; i += NT) {
        int g = i / HP, off = i - g * HP;
        float vi = 0.f, vh = 0.f;
        if (off < H) { vi = bih[g * H + off]; vh = bhh[g * H + off]; }
        sbih[i] = vi; sbhh[i] = vh;
    }
    if (t < SD)  sb1[t] = b1[t];
    if (t < 300) sw2[t] = W2[t];
    if (t < 6)   sb2[t] = b2[t];

    for (int grp = 0; grp < NGRP; ++grp) {
        const int bg0 = (grp * NBLK + blockIdx.x) * BT;
        __syncthreads();   // previous group's phases done before LDS reuse
        // zero state (h32, h16 hi/lo incl. pads, GI)
        for (int i = t; i < BT * H32S; i += NT) sh32[i] = 0.f;
        for (int i = t; i < BT * AHS / 2; i += NT) {
            ((unsigned*)(smc + OFF_HHI))[i] = 0u;
            ((unsigned*)(smc + OFF_HLO))[i] = 0u;
        }
        for (int i = t; i < BT * GIS; i += NT) sgi[i] = 0.f;
        if (t < 2 * BT) {
            sxp[t] = initp[bg0 * 2 + t];
            sdx[t] = initv[bg0 * 2 + t];
        }
        __syncthreads();
        // static -> fp16 into A-buffer cols 160..209
        for (int i = t; i < BT * SD; i += NT) {
            int b = i / SD, k = i - b * SD;
            shhi[b * AHS + HP + k] = (f16)statp[(bg0 + b) * SD + k];
        }
        __syncthreads();

        for (int step = 0; step < TSTEPS; ++step) {
            // ---- P1: gh = h @ W_hh^T via MFMA  (+ GI rank-2 update, merged) ----
            if (step > 0 && t < NP) {
                const float2 wv = ((const float2*)wihT)[(step - 1) * NP + t];
                #pragma unroll
                for (int b = 0; b < BT; ++b)
                    sgi[b * GIS + t] = fmaf(wv.x, sxc[2 * b],
                                        fmaf(wv.y, sxc[2 * b + 1], sgi[b * GIS + t]));
            }
            {
                f32x4 acc[4];
                #pragma unroll
                for (int c = 0; c < 4; ++c) acc[c] = (f32x4){0.f, 0.f, 0.f, 0.f};
                #pragma unroll
                for (int kk = 0; kk < 5; ++kk) {
                    f16x8 ahi = *(const f16x8*)(smc + OFF_HHI + lr * 464 + kk * 64 + lq * 16);
                    f16x8 alo = *(const f16x8*)(smc + OFF_HLO + lr * 464 + kk * 64 + lq * 16);
                    #pragma unroll
                    for (int c = 0; c < 4; ++c) {
                        if (w * 4 + c < 30) {
                            acc[c] = __builtin_amdgcn_mfma_f32_16x16x32_f16(ahi, bhi[c][kk], acc[c], 0, 0, 0);
                            acc[c] = __builtin_amdgcn_mfma_f32_16x16x32_f16(alo, bhi[c][kk], acc[c], 0, 0, 0);
                            acc[c] = __builtin_amdgcn_mfma_f32_16x16x32_f16(ahi, blo[c][kk], acc[c], 0, 0, 0);
                        }
                    }
                }
                #pragma unroll
                for (int c = 0; c < 4; ++c) {
                    const int ti = w * 4 + c;
                    if (ti < 30) {
                        #pragma unroll
                        for (int j = 0; j < 4; ++j)
                            sghs[(lq * 4 + j) * GIS + ti * 16 + lr] = acc[c][j];
                    }
                }
            }
            __syncthreads();

            // ---- P2: GRU gates + h update (fp32), write h fp16 hi/lo ----
            for (int it = t; it < BT * H; it += NT) {
                int b = it / H, u = it - b * H;
                float gir = sgi[b * GIS + u]          + sbih[u];
                float giz = sgi[b * GIS + u + HP]     + sbih[u + HP];
                float gin = sgi[b * GIS + u + 2 * HP] + sbih[u + 2 * HP];
                float ghr = sghs[b * GIS + u]          + sbhh[u];
                float ghz = sghs[b * GIS + u + HP]     + sbhh[u + HP];
                float ghn = sghs[b * GIS + u + 2 * HP] + sbhh[u + 2 * HP];
                float r  = 1.f / (1.f + expf(-(gir + ghr)));
                float zg = 1.f / (1.f + expf(-(giz + ghz)));
                float n  = tanhf(gin + r * ghn);
                float hv = (1.f - zg) * n + zg * sh32[b * H32S + u];
                sh32[b * H32S + u] = hv;
                f16 hh = (f16)hv;
                shhi[b * AHS + u] = hh;
                shlo[b * AHS + u] = (f16)(hv - (float)hh);
            }
            __syncthreads();

            // ---- P3: o1 = softplus(W1 @ [h,static] + b1) via MFMA (waves 0-3) ----
            if (w < 4) {
                f32x4 acc = (f32x4){0.f, 0.f, 0.f, 0.f};
                #pragma unroll
                for (int kk = 0; kk < 7; ++kk) {
                    f16x8 a  = *(const f16x8*)(smc + OFF_HHI + lr * 464 + kk * 64 + lq * 16);
                    f16x8 bb = *(const f16x8*)(smc + OFF_W1 + (w * 16 + lr) * 464 + kk * 64 + lq * 16);
                    acc = __builtin_amdgcn_mfma_f32_16x16x32_f16(a, bb, acc, 0, 0, 0);
                }
                const int col = w * 16 + lr;
                if (col < SD) {
                    #pragma unroll
                    for (int j = 0; j < 4; ++j)
                        so1[(lq * 4 + j) * O1S + col] = softplusf(acc[j] + sb1[col]);
                }
            }
            __syncthreads();

            // ---- P4: o2 = softplus(W2 @ o1 + b2), 96 threads ----
            if (t < BT * 6) {
                int b = t / 6, m = t - b * 6;
                float acc = sb2[m];
                #pragma unroll
                for (int k = 0; k < SD; ++k)
                    acc = fmaf(sw2[m * SD + k], so1[b * O1S + k], acc);
                so2[b * 8 + m] = softplusf(acc);
            }
            __syncthreads();

            // ---- P5: expm_sym2x2 + mu/x + global writes, 16 threads ----
            if (t < BT) {
                const int b  = t;
                const int bg = bg0 + b;
                float mh0 = so2[b * 8 + 0], mh1 = so2[b * 8 + 1];
                float s2 = so2[b * 8 + 2], s3 = so2[b * 8 + 3];
                float s4 = so2[b * 8 + 4], s5 = so2[b * 8 + 5];
                float a = 2.f * s2, bb2 = s3 + s4, c = 2.f * s5;
                float htr = 0.5f * (a + c), hdf = 0.5f * (a - c);
                float disc = sqrtf(hdf * hdf + bb2 * bb2);
                float d = fmaxf(disc, 1e-12f);
                float ep = expf(d), em = expf(-d);
                float sinhc = (0.5f * (ep - em)) / d;
                float coshd = 0.5f * (ep + em);
                float scale = expf(htr);
                float m00 = scale * (coshd + sinhc * hdf);
                float m11 = scale * (coshd - sinhc * hdf);
                float m01 = scale * (sinhc * bb2);

                float z0 = zp[(step * BTOT + bg) * 2 + 0];
                float z1 = zp[(step * BTOT + bg) * 2 + 1];
                float xp0 = sxp[2 * b], xp1 = sxp[2 * b + 1];
                float mu0 = xp0 + sdx[2 * b]     + mh0;
                float mu1 = xp1 + sdx[2 * b + 1] + mh1;
                float x0 = fmaf(m00, z0, fmaf(m01, z1, mu0));
                float x1 = fmaf(m01, z0, fmaf(m11, z1, mu1));

                const int oi = step * BTOT + bg;
                out[oi * 2 + 0] = mu0;
                out[oi * 2 + 1] = mu1;
                out[SIG_OFF + oi * 4 + 0] = m00;
                out[SIG_OFF + oi * 4 + 1] = m01;
                out[SIG_OFF + oi * 4 + 2] = m01;
                out[SIG_OFF + oi * 4 + 3] = m11;
                out[X_OFF + oi * 2 + 0] = x0;
                out[X_OFF + oi * 2 + 1] = x1;

                sxc[2 * b] = x0;        sxc[2 * b + 1] = x1;
                sdx[2 * b] = x0 - xp0;  sdx[2 * b + 1] = x1 - xp1;
                sxp[2 * b] = x0;        sxp[2 * b + 1] = x1;
            }
            __syncthreads();
        }
    }
}

extern "C" void kernel_launch(void* const* d_in, const int* in_sizes, int n_in,
                              void* d_out, int out_size, void* d_ws, size_t ws_size,
                              hipStream_t stream) {
    const float* statp = (const float*)d_in[0];
    const float* initv = (const float*)d_in[1];
    const float* initp = (const float*)d_in[2];
    const float* zp    = (const float*)d_in[3];
    const float* Wih   = (const float*)d_in[4];
    const float* Whh   = (const float*)d_in[5];
    const float* bih   = (const float*)d_in[6];
    const float* bhh   = (const float*)d_in[7];
    const float* W1    = (const float*)d_in[8];
    const float* b1    = (const float*)d_in[9];
    const float* W2    = (const float*)d_in[10];
    const float* b2    = (const float*)d_in[11];
    float* out = (float*)d_out;
    float* wihT = (float*)d_ws;   // 30*480*2 fp32 = 115200 B

    (void)hipFuncSetAttribute((const void*)r2p2_main,
                              hipFuncAttributeMaxDynamicSharedMemorySize,
                              SMEM_BYTES);

    r2p2_prep<<<(TSTEPS * NP + 255) / 256, 256, 0, stream>>>(Wih, wihT);
    r2p2_main<<<NBLK, NT, SMEM_BYTES, stream>>>(
        statp, initv, initp, zp, Whh, bih, bhh, W1, b1, W2, b2, wihT, out);
}

// Round 3
// 2239.504 us; speedup vs baseline: 42.8678x; 3.7620x over previous
//
#include <hip/hip_runtime.h>
#include <math.h>

// ---------------------------------------------------------------------------
// R2P2_Dynamic round 3: in-register GRU. Each wave owns N-tile "triples"
// {k, k+10, k+20} so r/z/n gates of one unit live in one lane (MFMA C-layout).
// gi (input-GEMM accumulator) and h live in registers; biases folded into gi.
// 3-barrier pipelined step: B0 gates | B1 MLP1 + next-step MFMA (w5-7) |
// B2 MLP2+expm+outputs (w4) + next-step MFMA (w0-3).
// ---------------------------------------------------------------------------

typedef _Float16 f16;
typedef _Float16 f16x8 __attribute__((ext_vector_type(8)));
typedef float    f32x4 __attribute__((ext_vector_type(4)));

constexpr int BTOT = 131072;
constexpr int TSTEPS = 30;
constexpr int H  = 150;
constexpr int SD = 50;
constexpr int BT = 16;
constexpr int NT = 512;
constexpr int NBLK = 256;
constexpr int NGRP = BTOT / (NBLK * BT);   // 32

constexpr int HP = 160;    // padded per-gate width
constexpr int NP = 480;    // padded 3H
constexpr int AHS = 232;   // f16 A-row stride: [h 0..149 |pad| static 160..209 |pad]

// workspace byte offsets
constexpr int WS_WIHT  = 0;          // 30*480*2 floats = 115200 B
constexpr int WS_BFRAG = 115200;     // 10*3*5*512 f16   = 153600 B

constexpr int SIG_OFF = TSTEPS * BTOT * 2;
constexpr int X_OFF   = SIG_OFF + TSTEPS * BTOT * 4;

__device__ __forceinline__ float fexp(float x)  { return __builtin_amdgcn_exp2f(x * 1.44269504f); }
__device__ __forceinline__ float sigm(float x)  { return __builtin_amdgcn_rcpf(1.f + __builtin_amdgcn_exp2f(-1.44269504f * x)); }
__device__ __forceinline__ float tanh_(float x) { return fmaf(-2.f, __builtin_amdgcn_rcpf(1.f + __builtin_amdgcn_exp2f(2.88539008f * x)), 1.f); }
__device__ __forceinline__ float softplus_(float v) {
    float e = __builtin_amdgcn_exp2f(-1.44269504f * fabsf(v));
    return fmaxf(v, 0.f) + 0.69314718f * __builtin_amdgcn_logf(1.f + e);
}

// --- prep1: W_ih [450][60] -> ws [30][480][2] fp32 (padded, gate-major) ----
__global__ void r2p2_prep(const float* __restrict__ Wih, float* __restrict__ ws) {
    int id = blockIdx.x * 256 + threadIdx.x;
    if (id >= TSTEPS * NP) return;
    int s = id / NP, tp = id - s * NP;
    int g = tp / HP, off = tp - g * HP;
    float2 v = make_float2(0.f, 0.f);
    if (off < H) {
        const float* row = Wih + (g * H + off) * (2 * TSTEPS);
        v.x = row[2 * s];
        v.y = row[2 * s + 1];
    }
    ((float2*)ws)[id] = v;
}

// --- prep2: W_hh -> fragment-order f16 [(k*3+g)*5+kk][lane][8] --------------
__global__ void r2p2_prep2(const float* __restrict__ Whh, f16* __restrict__ wsB) {
    int id = blockIdx.x * 256 + threadIdx.x;      // over 10*3*5*64 = 9600
    if (id >= 9600) return;
    int lane = id & 63, rest = id >> 6;           // rest = (k*3+g)*5+kk
    int kk = rest % 5, kg = rest / 5;
    int g = kg % 3, k = kg / 3;
    int lr = lane & 15, lq = lane >> 4;
    int nr = k * 16 + lr;
    f16x8 v;
    #pragma unroll
    for (int j = 0; j < 8; ++j) {
        int cc = kk * 32 + lq * 8 + j;
        float x = (nr < H && cc < H) ? Whh[(g * H + nr) * H + cc] : 0.f;
        v[j] = (f16)x;
    }
    *(f16x8*)(wsB + (size_t)id * 8) = v;
}

__global__ __launch_bounds__(NT, 2) void r2p2_main(
    const float* __restrict__ statp, const float* __restrict__ initv,
    const float* __restrict__ initp, const float* __restrict__ zp,
    const float* __restrict__ bih,   const float* __restrict__ bhh,
    const float* __restrict__ W1,    const float* __restrict__ b1,
    const float* __restrict__ W2,    const float* __restrict__ b2,
    const float* __restrict__ wihT,  const f16* __restrict__ wsB,
    float* __restrict__ out)
{
    __shared__ __align__(16) f16   sA[BT * AHS];      // h | pad | static
    __shared__ __align__(16) f16   sW1[64 * AHS];
    __shared__ __align__(16) f16   sO1[16 * 64];
    __shared__ __align__(16) f16   sW2[16 * 64];
    __shared__ __align__(16) float sO2[16 * 8];
    __shared__ __align__(16) float sZ[TSTEPS * 32];
    __shared__ __align__(16) float sXC[32];
    __shared__ __align__(16) float sXP[32];
    __shared__ __align__(16) float sDX[32];

    const int t  = threadIdx.x;
    const int w  = t >> 6;
    const int l  = t & 63;
    const int lr = l & 15;
    const int lq = l >> 4;

    // triple ownership: w0-3 -> {w}; w4 -> none; w5 -> {4,5}; w6 -> {6,7}; w7 -> {8,9}
    int ntr = 0, tr0 = 0;
    if (w < 4)       { ntr = 1; tr0 = w; }
    else if (w >= 5) { ntr = 2; tr0 = 4 + (w - 5) * 2; }

    // ---- one-time LDS init ----
    for (int i = t; i < BT * AHS / 2; i += NT) ((unsigned*)sA)[i] = 0u;
    for (int i = t; i < 64 * AHS; i += NT) {
        int r = i / AHS, k = i - r * AHS;
        float v = 0.f;
        if (r < SD && k < 224) {
            if (k < H) v = W1[r * 200 + k];
            else if (k >= HP && k < HP + SD) v = W1[r * 200 + H + (k - HP)];
        }
        sW1[i] = (f16)v;
    }
    for (int i = t; i < 16 * 64; i += NT) {
        int r = i / 64, k = i - r * 64;
        sW2[i] = (f16)((r < 6 && k < SD) ? W2[r * SD + k] : 0.f);
        sO1[i] = (f16)0.f;
    }

    // ---- one-time register loads ----
    f16x8 bfrag[2][3][5];
    #pragma unroll
    for (int tt = 0; tt < 2; ++tt) {
        if (tt < ntr) {
            int k = tr0 + tt;
            #pragma unroll
            for (int g = 0; g < 3; ++g)
                #pragma unroll
                for (int kk = 0; kk < 5; ++kk)
                    bfrag[tt][g][kk] = *(const f16x8*)(wsB + ((size_t)((k * 3 + g) * 5 + kk) * 64 + l) * 8);
        }
    }
    float cR[2], cZ[2], cNi[2], cNh[2];
    #pragma unroll
    for (int tt = 0; tt < 2; ++tt) {
        cR[tt] = cZ[tt] = cNi[tt] = cNh[tt] = 0.f;
        if (tt < ntr) {
            int u = (tr0 + tt) * 16 + lr;
            if (u < H) {
                cR[tt]  = bih[u]         + bhh[u];
                cZ[tt]  = bih[H + u]     + bhh[H + u];
                cNi[tt] = bih[2 * H + u];
                cNh[tt] = bhh[2 * H + u];
            }
        }
    }
    const int   p3col  = w * 16 + lr;
    const float b1reg  = (w < 4 && p3col < SD) ? b1[p3col] : 0.f;
    const float b2reg  = (lr < 6) ? b2[lr] : 0.f;

    float hreg[2][4];
    f32x4 acc[2][3];
    f32x4 gi[2][3];

    for (int grp = 0; grp < NGRP; ++grp) {
        const int bg0 = (grp * NBLK + blockIdx.x) * BT;
        __syncthreads();   // previous group fully done before LDS reuse
        // per-group LDS init
        for (int i = t; i < BT * SD; i += NT) {
            int b = i / SD, k = i - b * SD;
            sA[b * AHS + HP + k] = (f16)statp[(bg0 + b) * SD + k];
        }
        for (int i = t; i < TSTEPS * 32; i += NT)
            sZ[i] = zp[((size_t)(i >> 5) * BTOT + bg0) * 2 + (i & 31)];
        if (t < 2 * BT) {
            sXP[t] = initp[bg0 * 2 + t];
            sDX[t] = initv[bg0 * 2 + t];
        }
        // per-group register init
        #pragma unroll
        for (int tt = 0; tt < 2; ++tt) {
            #pragma unroll
            for (int j = 0; j < 4; ++j) hreg[tt][j] = 0.f;
            #pragma unroll
            for (int g = 0; g < 3; ++g) acc[tt][g] = (f32x4){0.f, 0.f, 0.f, 0.f};
            gi[tt][0] = (f32x4){cR[tt],  cR[tt],  cR[tt],  cR[tt]};
            gi[tt][1] = (f32x4){cZ[tt],  cZ[tt],  cZ[tt],  cZ[tt]};
            gi[tt][2] = (f32x4){cNi[tt], cNi[tt], cNi[tt], cNi[tt]};
        }
        __syncthreads();

        for (int s = 0; s < TSTEPS; ++s) {
            // ---- B0: gi rank-2 update (s>0) + in-register GRU gates ----
            if (ntr > 0) {
                if (s > 0) {
                    f32x4 xa = *(const f32x4*)&sXC[lq * 8];
                    f32x4 xb = *(const f32x4*)&sXC[lq * 8 + 4];
                    const float* wT = wihT + (size_t)(s - 1) * (NP * 2);
                    #pragma unroll
                    for (int tt = 0; tt < 2; ++tt) {
                        if (tt < ntr) {
                            int u = (tr0 + tt) * 16 + lr;
                            #pragma unroll
                            for (int g = 0; g < 3; ++g) {
                                float2 wv = *(const float2*)(wT + (g * HP + u) * 2);
                                gi[tt][g][0] = fmaf(wv.x, xa[0], fmaf(wv.y, xa[1], gi[tt][g][0]));
                                gi[tt][g][1] = fmaf(wv.x, xa[2], fmaf(wv.y, xa[3], gi[tt][g][1]));
                                gi[tt][g][2] = fmaf(wv.x, xb[0], fmaf(wv.y, xb[1], gi[tt][g][2]));
                                gi[tt][g][3] = fmaf(wv.x, xb[2], fmaf(wv.y, xb[3], gi[tt][g][3]));
                            }
                        }
                    }
                }
                #pragma unroll
                for (int tt = 0; tt < 2; ++tt) {
                    if (tt < ntr) {
                        int u = (tr0 + tt) * 16 + lr;
                        #pragma unroll
                        for (int j = 0; j < 4; ++j) {
                            float r  = sigm(acc[tt][0][j] + gi[tt][0][j]);
                            float zg = sigm(acc[tt][1][j] + gi[tt][1][j]);
                            float n  = tanh_(gi[tt][2][j] + r * (acc[tt][2][j] + cNh[tt]));
                            float hv = (1.f - zg) * n + zg * hreg[tt][j];
                            hreg[tt][j] = hv;
                            if (u < H) sA[(lq * 4 + j) * AHS + u] = (f16)hv;
                        }
                    }
                }
            }
            __syncthreads();

            // ---- B1: w0-3: MLP1 MFMA ; w5-7: next-step recurrent MFMA ----
            if (w < 4) {
                f32x4 a3 = (f32x4){0.f, 0.f, 0.f, 0.f};
                #pragma unroll
                for (int kk = 0; kk < 7; ++kk) {
                    f16x8 av = *(const f16x8*)(sA  + lr    * AHS + kk * 32 + lq * 8);
                    f16x8 bv = *(const f16x8*)(sW1 + p3col * AHS + kk * 32 + lq * 8);
                    a3 = __builtin_amdgcn_mfma_f32_16x16x32_f16(av, bv, a3, 0, 0, 0);
                }
                if (p3col < SD) {
                    #pragma unroll
                    for (int j = 0; j < 4; ++j)
                        sO1[(lq * 4 + j) * 64 + p3col] = (f16)softplus_(a3[j] + b1reg);
                }
            } else if (w >= 5 && s + 1 < TSTEPS) {
                f16x8 af[5];
                #pragma unroll
                for (int kk = 0; kk < 5; ++kk)
                    af[kk] = *(const f16x8*)(sA + lr * AHS + kk * 32 + lq * 8);
                #pragma unroll
                for (int tt = 0; tt < 2; ++tt) {
                    #pragma unroll
                    for (int g = 0; g < 3; ++g) {
                        acc[tt][g] = (f32x4){0.f, 0.f, 0.f, 0.f};
                        #pragma unroll
                        for (int kk = 0; kk < 5; ++kk)
                            acc[tt][g] = __builtin_amdgcn_mfma_f32_16x16x32_f16(af[kk], bfrag[tt][g][kk], acc[tt][g], 0, 0, 0);
                    }
                }
            }
            __syncthreads();

            // ---- B2: w4: MLP2 + expm + outputs ; w0-3: next-step MFMA ----
            if (w == 4) {
                f32x4 a4 = (f32x4){0.f, 0.f, 0.f, 0.f};
                #pragma unroll
                for (int kk = 0; kk < 2; ++kk) {
                    f16x8 av = *(const f16x8*)(sO1 + lr * 64 + kk * 32 + lq * 8);
                    f16x8 bv = *(const f16x8*)(sW2 + lr * 64 + kk * 32 + lq * 8);
                    a4 = __builtin_amdgcn_mfma_f32_16x16x32_f16(av, bv, a4, 0, 0, 0);
                }
                if (lr < 6) {
                    #pragma unroll
                    for (int j = 0; j < 4; ++j)
                        sO2[(lq * 4 + j) * 8 + lr] = softplus_(a4[j] + b2reg);
                }
                asm volatile("s_waitcnt lgkmcnt(0)" ::: "memory");
                if (l < BT) {
                    const int b  = l;
                    const int bg = bg0 + b;
                    f32x4  v0 = *(const f32x4*)&sO2[b * 8];
                    float2 v1 = *(const float2*)&sO2[b * 8 + 4];
                    float mh0 = v0[0], mh1 = v0[1];
                    float a = 2.f * v0[2], bb2 = v0[3] + v1.x, c = 2.f * v1.y;
                    float htr = 0.5f * (a + c), hdf = 0.5f * (a - c);
                    float disc = sqrtf(hdf * hdf + bb2 * bb2);
                    float d = fmaxf(disc, 1e-12f);
                    float ep = fexp(d), em = fexp(-d);
                    float sinhc = (0.5f * (ep - em)) * __builtin_amdgcn_rcpf(d);
                    float coshd = 0.5f * (ep + em);
                    float scale = fexp(htr);
                    float m00 = scale * (coshd + sinhc * hdf);
                    float m11 = scale * (coshd - sinhc * hdf);
                    float m01 = scale * (sinhc * bb2);

                    float z0 = sZ[s * 32 + 2 * b], z1 = sZ[s * 32 + 2 * b + 1];
                    float xp0 = sXP[2 * b], xp1 = sXP[2 * b + 1];
                    float mu0 = xp0 + sDX[2 * b]     + mh0;
                    float mu1 = xp1 + sDX[2 * b + 1] + mh1;
                    float x0 = fmaf(m00, z0, fmaf(m01, z1, mu0));
                    float x1 = fmaf(m01, z0, fmaf(m11, z1, mu1));

                    const size_t oi = (size_t)s * BTOT + bg;
                    *(float2*)(out + oi * 2) = make_float2(mu0, mu1);
                    *(float4*)(out + SIG_OFF + oi * 4) = make_float4(m00, m01, m01, m11);
                    *(float2*)(out + X_OFF + oi * 2) = make_float2(x0, x1);

                    sXC[2 * b] = x0;       sXC[2 * b + 1] = x1;
                    sDX[2 * b] = x0 - xp0; sDX[2 * b + 1] = x1 - xp1;
                    sXP[2 * b] = x0;       sXP[2 * b + 1] = x1;
                }
            } else if (w < 4 && s + 1 < TSTEPS) {
                f16x8 af[5];
                #pragma unroll
                for (int kk = 0; kk < 5; ++kk)
                    af[kk] = *(const f16x8*)(sA + lr * AHS + kk * 32 + lq * 8);
                #pragma unroll
                for (int g = 0; g < 3; ++g) {
                    acc[0][g] = (f32x4){0.f, 0.f, 0.f, 0.f};
                    #pragma unroll
                    for (int kk = 0; kk < 5; ++kk)
                        acc[0][g] = __builtin_amdgcn_mfma_f32_16x16x32_f16(af[kk], bfrag[0][g][kk], acc[0][g], 0, 0, 0);
                }
            }
            __syncthreads();
        }
    }
}

extern "C" void kernel_launch(void* const* d_in, const int* in_sizes, int n_in,
                              void* d_out, int out_size, void* d_ws, size_t ws_size,
                              hipStream_t stream) {
    const float* statp = (const float*)d_in[0];
    const float* initv = (const float*)d_in[1];
    const float* initp = (const float*)d_in[2];
    const float* zp    = (const float*)d_in[3];
    const float* Wih   = (const float*)d_in[4];
    const float* Whh   = (const float*)d_in[5];
    const float* bih   = (const float*)d_in[6];
    const float* bhh   = (const float*)d_in[7];
    const float* W1    = (const float*)d_in[8];
    const float* b1    = (const float*)d_in[9];
    const float* W2    = (const float*)d_in[10];
    const float* b2    = (const float*)d_in[11];
    float* out  = (float*)d_out;
    float* wihT = (float*)((char*)d_ws + WS_WIHT);
    f16*   wsB  = (f16*)  ((char*)d_ws + WS_BFRAG);

    r2p2_prep <<<(TSTEPS * NP + 255) / 256, 256, 0, stream>>>(Wih, wihT);
    r2p2_prep2<<<(9600 + 255) / 256, 256, 0, stream>>>(Whh, wsB);
    r2p2_main<<<NBLK, NT, 0, stream>>>(
        statp, initv, initp, zp, bih, bhh, W1, b1, W2, b2, wihT, wsB, out);
}

// Round 7
// 2190.844 us; speedup vs baseline: 43.8199x; 1.0222x over previous
//
#include <hip/hip_runtime.h>
#include <math.h>

// ---------------------------------------------------------------------------
// R2P2_Dynamic round 4 (3rd resubmit — three GPUAcquisitionTimeouts in a row):
// round-3 structure (in-register GRU, 3-barrier pipelined step) + latency
// fixes:
//  - outputs staged in LDS, flushed coalesced once per group (no per-step
//    vmcnt(0) store drain at barriers)
//  - wihT rank-2-update weights register-prefetched one step ahead
//  - sO1/sW2 row stride padded 64 -> 72 f16 (kills 32-way bank conflict)
// ---------------------------------------------------------------------------

typedef _Float16 f16;
typedef _Float16 f16x8 __attribute__((ext_vector_type(8)));
typedef float    f32x4 __attribute__((ext_vector_type(4)));

constexpr int BTOT = 131072;
constexpr int TSTEPS = 30;
constexpr int H  = 150;
constexpr int SD = 50;
constexpr int BT = 16;
constexpr int NT = 512;
constexpr int NBLK = 256;
constexpr int NGRP = BTOT / (NBLK * BT);   // 32

constexpr int HP = 160;    // padded per-gate width
constexpr int NP = 480;    // padded 3H
constexpr int AHS = 232;   // f16 A-row stride: [h 0..149 |pad| static 160..209 |pad]
constexpr int O1S = 72;    // padded o1 / W2 row stride (f16)

// workspace byte offsets
constexpr int WS_WIHT  = 0;          // 30*480*2 floats = 115200 B
constexpr int WS_BFRAG = 115200;     // 10*3*5*512 f16   = 153600 B

constexpr int SIG_OFF = TSTEPS * BTOT * 2;
constexpr int X_OFF   = SIG_OFF + TSTEPS * BTOT * 4;

__device__ __forceinline__ float fexp(float x)  { return __builtin_amdgcn_exp2f(x * 1.44269504f); }
__device__ __forceinline__ float sigm(float x)  { return __builtin_amdgcn_rcpf(1.f + __builtin_amdgcn_exp2f(-1.44269504f * x)); }
__device__ __forceinline__ float tanh_(float x) { return fmaf(-2.f, __builtin_amdgcn_rcpf(1.f + __builtin_amdgcn_exp2f(2.88539008f * x)), 1.f); }
__device__ __forceinline__ float softplus_(float v) {
    float e = __builtin_amdgcn_exp2f(-1.44269504f * fabsf(v));
    return fmaxf(v, 0.f) + 0.69314718f * __builtin_amdgcn_logf(1.f + e);
}

// --- prep1: W_ih [450][60] -> ws [30][480][2] fp32 (padded, gate-major) ----
__global__ void r2p2_prep(const float* __restrict__ Wih, float* __restrict__ ws) {
    int id = blockIdx.x * 256 + threadIdx.x;
    if (id >= TSTEPS * NP) return;
    int s = id / NP, tp = id - s * NP;
    int g = tp / HP, off = tp - g * HP;
    float2 v = make_float2(0.f, 0.f);
    if (off < H) {
        const float* row = Wih + (g * H + off) * (2 * TSTEPS);
        v.x = row[2 * s];
        v.y = row[2 * s + 1];
    }
    ((float2*)ws)[id] = v;
}

// --- prep2: W_hh -> fragment-order f16 [(k*3+g)*5+kk][lane][8] --------------
__global__ void r2p2_prep2(const float* __restrict__ Whh, f16* __restrict__ wsB) {
    int id = blockIdx.x * 256 + threadIdx.x;      // over 10*3*5*64 = 9600
    if (id >= 9600) return;
    int lane = id & 63, rest = id >> 6;           // rest = (k*3+g)*5+kk
    int kk = rest % 5, kg = rest / 5;
    int g = kg % 3, k = kg / 3;
    int lr = lane & 15, lq = lane >> 4;
    int nr = k * 16 + lr;
    f16x8 v;
    #pragma unroll
    for (int j = 0; j < 8; ++j) {
        int cc = kk * 32 + lq * 8 + j;
        float x = (nr < H && cc < H) ? Whh[(g * H + nr) * H + cc] : 0.f;
        v[j] = (f16)x;
    }
    *(f16x8*)(wsB + (size_t)id * 8) = v;
}

__global__ __launch_bounds__(NT, 2) void r2p2_main(
    const float* __restrict__ statp, const float* __restrict__ initv,
    const float* __restrict__ initp, const float* __restrict__ zp,
    const float* __restrict__ bih,   const float* __restrict__ bhh,
    const float* __restrict__ W1,    const float* __restrict__ b1,
    const float* __restrict__ W2,    const float* __restrict__ b2,
    const float* __restrict__ wihT,  const f16* __restrict__ wsB,
    float* __restrict__ out)
{
    __shared__ __align__(16) f16   sA[BT * AHS];      // h | pad | static
    __shared__ __align__(16) f16   sW1[64 * AHS];
    __shared__ __align__(16) f16   sO1[16 * O1S];
    __shared__ __align__(16) f16   sW2[16 * O1S];
    __shared__ __align__(16) float sO2[16 * 8];
    __shared__ __align__(16) float sZ[TSTEPS * 32];
    __shared__ __align__(16) float sOUT[TSTEPS * 16 * 8];   // mu0,mu1,m00,m01,m11,x0,x1,pad
    __shared__ __align__(16) float sXC[32];
    __shared__ __align__(16) float sXP[32];
    __shared__ __align__(16) float sDX[32];

    const int t  = threadIdx.x;
    const int w  = t >> 6;
    const int l  = t & 63;
    const int lr = l & 15;
    const int lq = l >> 4;

    // triple ownership: w0-3 -> {w}; w4 -> none; w5 -> {4,5}; w6 -> {6,7}; w7 -> {8,9}
    int ntr = 0, tr0 = 0;
    if (w < 4)       { ntr = 1; tr0 = w; }
    else if (w >= 5) { ntr = 2; tr0 = 4 + (w - 5) * 2; }

    // ---- one-time LDS init ----
    for (int i = t; i < BT * AHS / 2; i += NT) ((unsigned*)sA)[i] = 0u;
    for (int i = t; i < 64 * AHS; i += NT) {
        int r = i / AHS, k = i - r * AHS;
        float v = 0.f;
        if (r < SD && k < 224) {
            if (k < H) v = W1[r * 200 + k];
            else if (k >= HP && k < HP + SD) v = W1[r * 200 + H + (k - HP)];
        }
        sW1[i] = (f16)v;
    }
    for (int i = t; i < 16 * O1S; i += NT) {
        int r = i / O1S, k = i - r * O1S;
        sW2[i] = (f16)((r < 6 && k < SD) ? W2[r * SD + k] : 0.f);
        sO1[i] = (f16)0.f;
    }

    // ---- one-time register loads ----
    f16x8 bfrag[2][3][5];
    #pragma unroll
    for (int tt = 0; tt < 2; ++tt) {
        if (tt < ntr) {
            int k = tr0 + tt;
            #pragma unroll
            for (int g = 0; g < 3; ++g)
                #pragma unroll
                for (int kk = 0; kk < 5; ++kk)
                    bfrag[tt][g][kk] = *(const f16x8*)(wsB + ((size_t)((k * 3 + g) * 5 + kk) * 64 + l) * 8);
        }
    }
    float cR[2], cZ[2], cNi[2], cNh[2];
    #pragma unroll
    for (int tt = 0; tt < 2; ++tt) {
        cR[tt] = cZ[tt] = cNi[tt] = cNh[tt] = 0.f;
        if (tt < ntr) {
            int u = (tr0 + tt) * 16 + lr;
            if (u < H) {
                cR[tt]  = bih[u]         + bhh[u];
                cZ[tt]  = bih[H + u]     + bhh[H + u];
                cNi[tt] = bih[2 * H + u];
                cNh[tt] = bhh[2 * H + u];
            }
        }
    }
    const int   p3col  = w * 16 + lr;
    const float b1reg  = (w < 4 && p3col < SD) ? b1[p3col] : 0.f;
    const float b2reg  = (lr < 6) ? b2[lr] : 0.f;

    float hreg[2][4];
    f32x4 acc[2][3];
    f32x4 gi[2][3];
    float2 wvp[2][3];   // prefetched W_ih columns for next step's gi update

    for (int grp = 0; grp < NGRP; ++grp) {
        const int bg0 = (grp * NBLK + blockIdx.x) * BT;
        __syncthreads();   // previous group fully done (incl. flush) before LDS reuse
        // per-group LDS init
        for (int i = t; i < BT * SD; i += NT) {
            int b = i / SD, k = i - b * SD;
            sA[b * AHS + HP + k] = (f16)statp[(bg0 + b) * SD + k];
        }
        for (int i = t; i < TSTEPS * 32; i += NT)
            sZ[i] = zp[((size_t)(i >> 5) * BTOT + bg0) * 2 + (i & 31)];
        if (t < 2 * BT) {
            sXP[t] = initp[bg0 * 2 + t];
            sDX[t] = initv[bg0 * 2 + t];
        }
        // per-group register init
        #pragma unroll
        for (int tt = 0; tt < 2; ++tt) {
            #pragma unroll
            for (int j = 0; j < 4; ++j) hreg[tt][j] = 0.f;
            #pragma unroll
            for (int g = 0; g < 3; ++g) acc[tt][g] = (f32x4){0.f, 0.f, 0.f, 0.f};
            gi[tt][0] = (f32x4){cR[tt],  cR[tt],  cR[tt],  cR[tt]};
            gi[tt][1] = (f32x4){cZ[tt],  cZ[tt],  cZ[tt],  cZ[tt]};
            gi[tt][2] = (f32x4){cNi[tt], cNi[tt], cNi[tt], cNi[tt]};
        }
        __syncthreads();

        for (int s = 0; s < TSTEPS; ++s) {
            // ---- B0: gi rank-2 update (s>0, weights prefetched) + gates ----
            if (ntr > 0) {
                if (s > 0) {
                    f32x4 xa = *(const f32x4*)&sXC[lq * 8];
                    f32x4 xb = *(const f32x4*)&sXC[lq * 8 + 4];
                    #pragma unroll
                    for (int tt = 0; tt < 2; ++tt) {
                        if (tt < ntr) {
                            #pragma unroll
                            for (int g = 0; g < 3; ++g) {
                                float2 wv = wvp[tt][g];
                                gi[tt][g][0] = fmaf(wv.x, xa[0], fmaf(wv.y, xa[1], gi[tt][g][0]));
                                gi[tt][g][1] = fmaf(wv.x, xa[2], fmaf(wv.y, xa[3], gi[tt][g][1]));
                                gi[tt][g][2] = fmaf(wv.x, xb[0], fmaf(wv.y, xb[1], gi[tt][g][2]));
                                gi[tt][g][3] = fmaf(wv.x, xb[2], fmaf(wv.y, xb[3], gi[tt][g][3]));
                            }
                        }
                    }
                }
                #pragma unroll
                for (int tt = 0; tt < 2; ++tt) {
                    if (tt < ntr) {
                        int u = (tr0 + tt) * 16 + lr;
                        #pragma unroll
                        for (int j = 0; j < 4; ++j) {
                            float r  = sigm(acc[tt][0][j] + gi[tt][0][j]);
                            float zg = sigm(acc[tt][1][j] + gi[tt][1][j]);
                            float n  = tanh_(gi[tt][2][j] + r * (acc[tt][2][j] + cNh[tt]));
                            float hv = (1.f - zg) * n + zg * hreg[tt][j];
                            hreg[tt][j] = hv;
                            if (u < H) sA[(lq * 4 + j) * AHS + u] = (f16)hv;
                        }
                    }
                }
            }
            __syncthreads();

            // prefetch next step's W_ih columns (independent of LDS state;
            // latency hides behind B1 MFMAs + barrier + B2)
            if (ntr > 0 && s + 1 < TSTEPS) {
                const float* wT = wihT + (size_t)s * (NP * 2);
                #pragma unroll
                for (int tt = 0; tt < 2; ++tt) {
                    if (tt < ntr) {
                        int u = (tr0 + tt) * 16 + lr;
                        #pragma unroll
                        for (int g = 0; g < 3; ++g)
                            wvp[tt][g] = *(const float2*)(wT + (g * HP + u) * 2);
                    }
                }
            }

            // ---- B1: w0-3: MLP1 MFMA ; w5-7: next-step recurrent MFMA ----
            if (w < 4) {
                f32x4 a3 = (f32x4){0.f, 0.f, 0.f, 0.f};
                #pragma unroll
                for (int kk = 0; kk < 7; ++kk) {
                    f16x8 av = *(const f16x8*)(sA  + lr    * AHS + kk * 32 + lq * 8);
                    f16x8 bv = *(const f16x8*)(sW1 + p3col * AHS + kk * 32 + lq * 8);
                    a3 = __builtin_amdgcn_mfma_f32_16x16x32_f16(av, bv, a3, 0, 0, 0);
                }
                if (p3col < SD) {
                    #pragma unroll
                    for (int j = 0; j < 4; ++j)
                        sO1[(lq * 4 + j) * O1S + p3col] = (f16)softplus_(a3[j] + b1reg);
                }
            } else if (w >= 5 && s + 1 < TSTEPS) {
                f16x8 af[5];
                #pragma unroll
                for (int kk = 0; kk < 5; ++kk)
                    af[kk] = *(const f16x8*)(sA + lr * AHS + kk * 32 + lq * 8);
                #pragma unroll
                for (int tt = 0; tt < 2; ++tt) {
                    #pragma unroll
                    for (int g = 0; g < 3; ++g) {
                        acc[tt][g] = (f32x4){0.f, 0.f, 0.f, 0.f};
                        #pragma unroll
                        for (int kk = 0; kk < 5; ++kk)
                            acc[tt][g] = __builtin_amdgcn_mfma_f32_16x16x32_f16(af[kk], bfrag[tt][g][kk], acc[tt][g], 0, 0, 0);
                    }
                }
            }
            __syncthreads();

            // ---- B2: w4: MLP2 + expm + stage ; w0-3: next-step MFMA ----
            if (w == 4) {
                f32x4 a4 = (f32x4){0.f, 0.f, 0.f, 0.f};
                #pragma unroll
                for (int kk = 0; kk < 2; ++kk) {
                    f16x8 av = *(const f16x8*)(sO1 + lr * O1S + kk * 32 + lq * 8);
                    f16x8 bv = *(const f16x8*)(sW2 + lr * O1S + kk * 32 + lq * 8);
                    a4 = __builtin_amdgcn_mfma_f32_16x16x32_f16(av, bv, a4, 0, 0, 0);
                }
                if (lr < 6) {
                    #pragma unroll
                    for (int j = 0; j < 4; ++j)
                        sO2[(lq * 4 + j) * 8 + lr] = softplus_(a4[j] + b2reg);
                }
                asm volatile("s_waitcnt lgkmcnt(0)" ::: "memory");
                if (l < BT) {
                    const int b = l;
                    f32x4  v0 = *(const f32x4*)&sO2[b * 8];
                    float2 v1 = *(const float2*)&sO2[b * 8 + 4];
                    float mh0 = v0[0], mh1 = v0[1];
                    float a = 2.f * v0[2], bb2 = v0[3] + v1.x, c = 2.f * v1.y;
                    float htr = 0.5f * (a + c), hdf = 0.5f * (a - c);
                    float disc = sqrtf(hdf * hdf + bb2 * bb2);
                    float d = fmaxf(disc, 1e-12f);
                    float ep = fexp(d), em = fexp(-d);
                    float sinhc = (0.5f * (ep - em)) * __builtin_amdgcn_rcpf(d);
                    float coshd = 0.5f * (ep + em);
                    float scale = fexp(htr);
                    float m00 = scale * (coshd + sinhc * hdf);
                    float m11 = scale * (coshd - sinhc * hdf);
                    float m01 = scale * (sinhc * bb2);

                    float z0 = sZ[s * 32 + 2 * b], z1 = sZ[s * 32 + 2 * b + 1];
                    float xp0 = sXP[2 * b], xp1 = sXP[2 * b + 1];
                    float mu0 = xp0 + sDX[2 * b]     + mh0;
                    float mu1 = xp1 + sDX[2 * b + 1] + mh1;
                    float x0 = fmaf(m00, z0, fmaf(m01, z1, mu0));
                    float x1 = fmaf(m01, z0, fmaf(m11, z1, mu1));

                    float* st = &sOUT[(s * 16 + b) * 8];
                    *(float4*)(st)     = make_float4(mu0, mu1, m00, m01);
                    *(float4*)(st + 4) = make_float4(m11, x0, x1, 0.f);

                    sXC[2 * b] = x0;       sXC[2 * b + 1] = x1;
                    sDX[2 * b] = x0 - xp0; sDX[2 * b + 1] = x1 - xp1;
                    sXP[2 * b] = x0;       sXP[2 * b + 1] = x1;
                }
            } else if (w < 4 && s + 1 < TSTEPS) {
                f16x8 af[5];
                #pragma unroll
                for (int kk = 0; kk < 5; ++kk)
                    af[kk] = *(const f16x8*)(sA + lr * AHS + kk * 32 + lq * 8);
                #pragma unroll
                for (int g = 0; g < 3; ++g) {
                    acc[0][g] = (f32x4){0.f, 0.f, 0.f, 0.f};
                    #pragma unroll
                    for (int kk = 0; kk < 5; ++kk)
                        acc[0][g] = __builtin_amdgcn_mfma_f32_16x16x32_f16(af[kk], bfrag[0][g][kk], acc[0][g], 0, 0, 0);
                }
            }
            __syncthreads();
        }

        // ---- group flush: coalesced output writes (one store drain/group) ----
        if (t < TSTEPS * 16) {
            int s = t >> 4, b = t & 15;
            const float* src = &sOUT[(s * 16 + b) * 8];
            const size_t oi = (size_t)s * BTOT + bg0 + b;
            *(float2*)(out + oi * 2)           = make_float2(src[0], src[1]);
            *(float4*)(out + SIG_OFF + oi * 4) = make_float4(src[2], src[3], src[3], src[4]);
            *(float2*)(out + X_OFF + oi * 2)   = make_float2(src[5], src[6]);
        }
    }
}

extern "C" void kernel_launch(void* const* d_in, const int* in_sizes, int n_in,
                              void* d_out, int out_size, void* d_ws, size_t ws_size,
                              hipStream_t stream) {
    const float* statp = (const float*)d_in[0];
    const float* initv = (const float*)d_in[1];
    const float* initp = (const float*)d_in[2];
    const float* zp    = (const float*)d_in[3];
    const float* Wih   = (const float*)d_in[4];
    const float* Whh   = (const float*)d_in[5];
    const float* bih   = (const float*)d_in[6];
    const float* bhh   = (const float*)d_in[7];
    const float* W1    = (const float*)d_in[8];
    const float* b1    = (const float*)d_in[9];
    const float* W2    = (const float*)d_in[10];
    const float* b2    = (const float*)d_in[11];
    float* out  = (float*)d_out;
    float* wihT = (float*)((char*)d_ws + WS_WIHT);
    f16*   wsB  = (f16*)  ((char*)d_ws + WS_BFRAG);

    r2p2_prep <<<(TSTEPS * NP + 255) / 256, 256, 0, stream>>>(Wih, wihT);
    r2p2_prep2<<<(9600 + 255) / 256, 256, 0, stream>>>(Whh, wsB);
    r2p2_main<<<NBLK, NT, 0, stream>>>(
        statp, initv, initp, zp, bih, bhh, W1, b1, W2, b2, wihT, wsB, out);
}